// Round 1
// 173.549 us; speedup vs baseline: 1.0028x; 1.0028x over previous
//
#include <hip/hip_runtime.h>

// LengthRegulator: B=32, T=512, D=512, max_len=2048 (fixed by the problem).
// out[b, t, :] = x[b, searchsorted_right(cumsum(duration[b]), t), :] for
// t < sum(duration[b]), else zeros. mel_lengths[b] = max(sum, 1), stored as
// float at the tail of d_out (harness reads whole buffer as float32).
//
// Two-kernel design (same stream, graph-capture safe):
//   A) lr_scan_kernel: 32 blocks (one per batch). Wave-level shfl scan of
//      duration (1 barrier vs the old 18-barrier Hillis-Steele), then each
//      phoneme-thread SCATTERS its own index into the frame->phoneme table
//      idxt[b][t] in d_ws (no binary search at all); -1 marks padding.
//   B) lr_copy_kernel: pure streamer. No LDS, no barriers. Each wave handles
//      4 consecutive frames per iteration: one wave-uniform int4 index fetch
//      (L2-hot, 16 B per 8 KiB moved), 2 coalesced f4 loads + 2 nontemporal
//      f4 stores per frame. 2048 blocks x 256 threads = 32 waves/CU at low
//      VGPR -> max outstanding stores.

#define BB      32
#define TT      512
#define DD      512
#define MAXLEN  2048

typedef float f4 __attribute__((ext_vector_type(4)));
typedef int   i4 __attribute__((ext_vector_type(4)));

__global__ __launch_bounds__(512) void lr_scan_kernel(
    const int* __restrict__ dur, int* __restrict__ idxt,
    float* __restrict__ mel_out) {
  __shared__ int wsum[8];
  const int b    = blockIdx.x;
  const int tid  = threadIdx.x;
  const int lane = tid & 63;
  const int wid  = tid >> 6;

  const int d = dur[b * TT + tid];
  int v = d;
  // Inclusive scan within the 64-lane wave (6 shfl steps, no barriers).
#pragma unroll
  for (int off = 1; off < 64; off <<= 1) {
    int n = __shfl_up(v, off, 64);
    if (lane >= off) v += n;
  }
  if (lane == 63) wsum[wid] = v;
  __syncthreads();

  int woff = 0, dsum = 0;
#pragma unroll
  for (int i = 0; i < 8; ++i) {
    int w = wsum[i];
    dsum += w;
    if (i < wid) woff += w;
  }
  v += woff;  // inclusive cumsum at phoneme tid

  if (tid == 0) mel_out[b] = (float)(dsum > 1 ? dsum : 1);

  // Scatter: phoneme tid owns output frames [v - d, v), truncated at MAXLEN.
  // Union over threads is exactly [0, min(dsum, MAXLEN)) -- no search needed.
  int start = v - d;
  int end   = v;
  if (start > MAXLEN) start = MAXLEN;
  if (end   > MAXLEN) end   = MAXLEN;
  int* row = idxt + b * MAXLEN;
  for (int t = start; t < end; ++t) row[t] = tid;
  // Padding tail [dsum, MAXLEN): coalesced -1 fill.
  for (int t = dsum + tid; t < MAXLEN; t += TT) row[t] = -1;
}

__global__ __launch_bounds__(256) void lr_copy_kernel(
    const int* __restrict__ idxt, const f4* __restrict__ x,
    f4* __restrict__ out) {
  const int lane    = threadIdx.x & 63;
  const int gwave   = blockIdx.x * (256 / 64) + (threadIdx.x >> 6);
  const int nwaves  = gridDim.x * (256 / 64);          // 8192
  const int ngroups = (BB * MAXLEN) / 4;               // 16384 groups of 4 frames
  const f4 zero = {0.f, 0.f, 0.f, 0.f};

  for (int grp = gwave; grp < ngroups; grp += nwaves) {
    const int b  = grp >> 9;            // 512 groups per batch
    const int t0 = (grp & 511) * 4;
    const i4 idx4 = *(const i4*)&idxt[b * MAXLEN + t0];  // wave-uniform, L2-hot
    const f4* xb = x + (size_t)b * (TT * (DD / 4));
    f4* ob = out + ((size_t)b * MAXLEN + t0) * (DD / 4) + lane;
#pragma unroll
    for (int f = 0; f < 4; ++f) {
      const int idx = idx4[f];          // wave-uniform -> no divergence
      f4 v0 = zero, v1 = zero;
      if (idx >= 0) {
        const f4* xr = xb + (size_t)idx * (DD / 4) + lane;
        v0 = xr[0];
        v1 = xr[64];
      }
      __builtin_nontemporal_store(v0, ob + f * (DD / 4));
      __builtin_nontemporal_store(v1, ob + f * (DD / 4) + 64);
    }
  }
}

extern "C" void kernel_launch(void* const* d_in, const int* in_sizes, int n_in,
                              void* d_out, int out_size, void* d_ws, size_t ws_size,
                              hipStream_t stream) {
  const float* x   = (const float*)d_in[0];
  const int*   dur = (const int*)d_in[1];
  // d_in[2] is max_len (=2048), static; hard-coded.
  float* out = (float*)d_out;
  float* mel_out = out + (size_t)BB * MAXLEN * DD;  // tail: 32 floats
  int* idxt = (int*)d_ws;                           // 32*2048*4 = 256 KiB

  lr_scan_kernel<<<BB, 512, 0, stream>>>(dur, idxt, mel_out);
  lr_copy_kernel<<<2048, 256, 0, stream>>>(idxt, (const f4*)x, (f4*)out);
}

// Round 2
// 163.961 us; speedup vs baseline: 1.0614x; 1.0585x over previous
//
#include <hip/hip_runtime.h>

// LengthRegulator: B=32, T=512, D=512, max_len=2048 (fixed by the problem).
// out[b, t, :] = x[b, searchsorted_right(cumsum(duration[b]), t), :] for
// t < sum(duration[b]), else zeros. mel_lengths[b] = max(sum, 1), stored as
// float at the tail of d_out (harness reads whole buffer as float32).
//
// SCATTER formulation (single kernel, no workspace):
//   Phoneme j covers output frames [cs[j-1], cs[j]) -- exactly the
//   searchsorted_right semantics. So instead of gather (frame -> dependent
//   idx load -> indirect x-row read), each wave owns one phoneme: it reads
//   its 2 KiB x row ONCE with linear coalesced loads (x streamed exactly
//   once, no L2 re-reads, no index table, no dependent-load chain) and
//   stores the row to its contiguous frame range with plain stores (the
//   poison fill proves plain streaming stores reach 6.2 TB/s).
//
//   Grid: 32 blocks per batch x 32 batches = 1024 blocks x 512 threads
//   (4 blocks/CU x 8 waves = full 32 waves/CU; LDS 2 KiB). Each block
//   redundantly shfl-scans duration[b,:] (round 0 proved redundant scans
//   are free; 1-barrier wave scan vs 18-barrier Hillis-Steele). Block sub
//   owns phonemes [sub*16, sub*16+16), 2 per wave. Padding frames
//   [dsum, 2048) are zeroed by per-(block,wave) slots with stride 256.

#define BB      32
#define TT      512
#define DD      512
#define MAXLEN  2048
#define RPF     (DD / 4)   // 128 float4 per frame row

typedef float f4 __attribute__((ext_vector_type(4)));

__global__ __launch_bounds__(512) void lr_scatter_kernel(
    const int* __restrict__ dur, const f4* __restrict__ x,
    f4* __restrict__ out, float* __restrict__ mel_out) {
  __shared__ int s[TT];     // inclusive cumsum of duration[b,:]
  __shared__ int wsum[8];

  const int bid  = blockIdx.x;
  const int b    = bid >> 5;        // 32 blocks per batch
  const int sub  = bid & 31;
  const int tid  = threadIdx.x;
  const int lane = tid & 63;
  const int wid  = tid >> 6;

  // --- cumsum via wave shfl scan (1 barrier) ---
  int v = dur[b * TT + tid];
#pragma unroll
  for (int off = 1; off < 64; off <<= 1) {
    int n = __shfl_up(v, off, 64);
    if (lane >= off) v += n;
  }
  if (lane == 63) wsum[wid] = v;
  __syncthreads();
  int woff = 0, dsum = 0;
#pragma unroll
  for (int i = 0; i < 8; ++i) {
    int w = wsum[i];
    dsum += w;
    if (i < wid) woff += w;
  }
  v += woff;
  s[tid] = v;          // inclusive cumsum at phoneme tid
  __syncthreads();

  if (sub == 0 && tid == 0) {
    mel_out[b] = (float)(dsum > 1 ? dsum : 1);
  }

  const f4* xb = x + (size_t)b * TT * RPF;
  f4* ob       = out + (size_t)b * MAXLEN * RPF;

  // --- scatter: wave (sub, wid) owns phonemes j = sub*16 + wid*2 + {0,1} ---
#pragma unroll
  for (int jj = 0; jj < 2; ++jj) {
    const int j = (sub << 4) + (wid << 1) + jj;
    int start = (j > 0) ? s[j - 1] : 0;
    int end   = s[j];
    if (start > MAXLEN) start = MAXLEN;
    if (end   > MAXLEN) end   = MAXLEN;
    if (end > start) {
      const f4* xr = xb + (size_t)j * RPF + lane;
      const f4 v0 = xr[0];
      const f4 v1 = xr[64];
      f4* o = ob + (size_t)start * RPF + lane;
      for (int t = start; t < end; ++t, o += RPF) {
        o[0]  = v0;
        o[64] = v1;
      }
    }
  }

  // --- padding tail: frames [dsum, MAXLEN) zeroed, slot-strided ---
  const f4 zero = {0.f, 0.f, 0.f, 0.f};
  const int slot = (sub << 3) + wid;   // 0..255 per batch
  for (int t = dsum + slot; t < MAXLEN; t += 256) {
    f4* o = ob + (size_t)t * RPF + lane;
    o[0]  = zero;
    o[64] = zero;
  }
}

extern "C" void kernel_launch(void* const* d_in, const int* in_sizes, int n_in,
                              void* d_out, int out_size, void* d_ws, size_t ws_size,
                              hipStream_t stream) {
  const float* x   = (const float*)d_in[0];
  const int*   dur = (const int*)d_in[1];
  // d_in[2] is max_len (=2048), static; hard-coded.
  float* out = (float*)d_out;
  float* mel_out = out + (size_t)BB * MAXLEN * DD;  // tail: 32 floats

  lr_scatter_kernel<<<BB * 32, 512, 0, stream>>>(
      dur, (const f4*)x, (f4*)out, mel_out);
}